// Round 7
// baseline (275.286 us; speedup 1.0000x reference)
//
#include <hip/hip_runtime.h>
#include <math.h>

// ---------------- conv1: (512,1,32,32) -> conv3x3(32ch) -> BN -> ReLU -> pool2 -> h1 (512,32,15,15)
__global__ __launch_bounds__(512) void conv1_k(
    const float* __restrict__ x, const float* __restrict__ w,
    const float* __restrict__ cb, const float* __restrict__ bg,
    const float* __restrict__ bb, const float* __restrict__ bm,
    const float* __restrict__ bv, float* __restrict__ h1)
{
    __shared__ float img[32 * 33];            // row stride 33 -> conflict-free broadcast reads
    __shared__ float ws_[288];
    __shared__ float scale[32], bias2[32];
    const int b = blockIdx.x, tid = threadIdx.x;
    for (int i = tid; i < 1024; i += 512) {
        const int y = i >> 5, xx = i & 31;
        img[y * 33 + xx] = x[b * 1024 + i];
    }
    if (tid < 288) ws_[tid] = w[tid];
    if (tid < 32) {
        float inv = bg[tid] / sqrtf(bv[tid] + 1e-5f);
        scale[tid] = inv;
        bias2[tid] = (cb[tid] - bm[tid]) * inv + bb[tid];
    }
    __syncthreads();

    const int co = tid >> 4, py = tid & 15;
    if (py < 15) {
        float acc0[30], acc1[30];
        #pragma unroll
        for (int i = 0; i < 30; ++i) { acc0[i] = 0.f; acc1[i] = 0.f; }
        const float* w9 = &ws_[co * 9];
        #pragma unroll
        for (int ir = 0; ir < 4; ++ir) {
            const int y = 2 * py + ir;
            float wk0 = 0.f, wk1 = 0.f, wk2 = 0.f, wl0 = 0.f, wl1 = 0.f, wl2 = 0.f;
            if (ir <= 2) { wk0 = w9[ir * 3 + 0]; wk1 = w9[ir * 3 + 1]; wk2 = w9[ir * 3 + 2]; }
            if (ir >= 1) { wl0 = w9[(ir - 1) * 3 + 0]; wl1 = w9[(ir - 1) * 3 + 1]; wl2 = w9[(ir - 1) * 3 + 2]; }
            #pragma unroll
            for (int xx = 0; xx < 32; ++xx) {
                const float rv = img[y * 33 + xx];
                if (ir <= 2) {
                    if (xx <= 29) acc0[xx] += rv * wk0;
                    if (xx >= 1 && xx <= 30) acc0[xx - 1] += rv * wk1;
                    if (xx >= 2) acc0[xx - 2] += rv * wk2;
                }
                if (ir >= 1) {
                    if (xx <= 29) acc1[xx] += rv * wl0;
                    if (xx >= 1 && xx <= 30) acc1[xx - 1] += rv * wl1;
                    if (xx >= 2) acc1[xx - 2] += rv * wl2;
                }
            }
        }
        const float sc = scale[co], bs = bias2[co];
        #pragma unroll
        for (int px = 0; px < 15; ++px) {
            const float v = fmaxf(acc0[2 * px] * sc + bs, 0.f)
                          + fmaxf(acc0[2 * px + 1] * sc + bs, 0.f)
                          + fmaxf(acc1[2 * px] * sc + bs, 0.f)
                          + fmaxf(acc1[2 * px + 1] * sc + bs, 0.f);
            h1[b * 7200 + co * 225 + py * 15 + px] = v * 0.25f;
        }
    }
}

// ---------------- conv2: h1 (512,32,15,15) -> conv3x3(32ch) -> BN -> ReLU -> pool2 -> h2 (512,32,6,6)
__global__ __launch_bounds__(384) void conv2_k(
    const float* __restrict__ h1, const float* __restrict__ w,
    const float* __restrict__ cb, const float* __restrict__ bg,
    const float* __restrict__ bb, const float* __restrict__ bm,
    const float* __restrict__ bv, float* __restrict__ h2)
{
    __shared__ float in_s[32 * 210];
    __shared__ float w_s[9216];               // transposed: w_s[k*32 + co]
    __shared__ float scale[32], bias2[32];
    const int b = blockIdx.x, tid = threadIdx.x;
    for (int i = tid; i < 6720; i += 384) {
        const int ci = i / 210, rem = i % 210;
        in_s[i] = h1[b * 7200 + ci * 225 + rem];
    }
    for (int i = tid; i < 9216; i += 384) {
        const int co = i & 31, k = i >> 5;
        w_s[i] = w[co * 288 + k];
    }
    if (tid < 32) {
        float inv = bg[tid] / sqrtf(bv[tid] + 1e-5f);
        scale[tid] = inv;
        bias2[tid] = (cb[tid] - bm[tid]) * inv + bb[tid];
    }
    __syncthreads();

    const int co = tid & 31, g = tid >> 5;
    const int py = g >> 1, xh = g & 1;
    const int gx0 = xh * 6;
    float acc0[6], acc1[6];
    #pragma unroll
    for (int i = 0; i < 6; ++i) { acc0[i] = 0.f; acc1[i] = 0.f; }

    for (int ci = 0; ci < 32; ++ci) {
        float w9[9];
        #pragma unroll
        for (int kk = 0; kk < 9; ++kk) w9[kk] = w_s[(ci * 9 + kk) * 32 + co];
        const float* ip = &in_s[ci * 210];
        #pragma unroll
        for (int ir = 0; ir < 4; ++ir) {
            const int y = 2 * py + ir;
            const float* rowp = &ip[y * 15 + gx0];
            #pragma unroll
            for (int xx = 0; xx < 8; ++xx) {
                const float rv = rowp[xx];
                if (ir <= 2) {
                    if (xx <= 5) acc0[xx] += rv * w9[ir * 3 + 0];
                    if (xx >= 1 && xx <= 6) acc0[xx - 1] += rv * w9[ir * 3 + 1];
                    if (xx >= 2) acc0[xx - 2] += rv * w9[ir * 3 + 2];
                }
                if (ir >= 1) {
                    if (xx <= 5) acc1[xx] += rv * w9[(ir - 1) * 3 + 0];
                    if (xx >= 1 && xx <= 6) acc1[xx - 1] += rv * w9[(ir - 1) * 3 + 1];
                    if (xx >= 2) acc1[xx - 2] += rv * w9[(ir - 1) * 3 + 2];
                }
            }
        }
    }
    const float sc = scale[co], bs = bias2[co];
    #pragma unroll
    for (int pxl = 0; pxl < 3; ++pxl) {
        const float v = fmaxf(acc0[2 * pxl] * sc + bs, 0.f)
                      + fmaxf(acc0[2 * pxl + 1] * sc + bs, 0.f)
                      + fmaxf(acc1[2 * pxl] * sc + bs, 0.f)
                      + fmaxf(acc1[2 * pxl + 1] * sc + bs, 0.f);
        h2[b * 1152 + co * 36 + py * 6 + xh * 3 + pxl] = v * 0.25f;
    }
}

// ---------------- conv3: h2 (512,32,6,6) -> conv3x3(32ch) -> BN -> ReLU -> pool2 -> feat (512,128)
// v2: transposed weights in LDS (conflict-free), 256 threads = (ci-half h, pos, co), psum combine.
__global__ __launch_bounds__(256) void conv3_k(
    const float* __restrict__ h2, const float* __restrict__ w,
    const float* __restrict__ cb, const float* __restrict__ bg,
    const float* __restrict__ bb, const float* __restrict__ bm,
    const float* __restrict__ bv, float* __restrict__ feat)
{
    __shared__ float in_s[1152];
    __shared__ float w_s[9216];               // w_s[k*32 + co], k = ci*9 + kk
    __shared__ float psum[2][4][4][33];       // [h][pos][k][co], stride-33 pad
    __shared__ float scale[32], bias2[32];
    const int b = blockIdx.x, tid = threadIdx.x;
    for (int i = tid; i < 1152; i += 256) in_s[i] = h2[b * 1152 + i];
    for (int i = tid; i < 9216; i += 256) {
        const int co = i & 31, k = i >> 5;
        w_s[i] = w[co * 288 + k];
    }
    if (tid < 32) {
        float inv = bg[tid] / sqrtf(bv[tid] + 1e-5f);
        scale[tid] = inv;
        bias2[tid] = (cb[tid] - bm[tid]) * inv + bb[tid];
    }
    __syncthreads();

    const int co = tid & 31, g = tid >> 5;
    const int pos = g & 3, h = g >> 2;        // pos = py*2+px, h = ci half
    const int y0 = (pos >> 1) * 2, x0 = (pos & 1) * 2;
    float s00 = 0.f, s01 = 0.f, s10 = 0.f, s11 = 0.f;
    for (int ci = h * 16; ci < h * 16 + 16; ++ci) {
        float w9[9];
        #pragma unroll
        for (int kk = 0; kk < 9; ++kk) w9[kk] = w_s[(ci * 9 + kk) * 32 + co];
        const float* ip = &in_s[ci * 36 + y0 * 6 + x0];
        float p[4][4];
        #pragma unroll
        for (int i = 0; i < 4; ++i)
            #pragma unroll
            for (int j = 0; j < 4; ++j)
                p[i][j] = ip[i * 6 + j];
        #pragma unroll
        for (int ky = 0; ky < 3; ++ky)
            #pragma unroll
            for (int kx = 0; kx < 3; ++kx) {
                const float wv = w9[ky * 3 + kx];
                s00 += p[ky][kx] * wv;
                s01 += p[ky][kx + 1] * wv;
                s10 += p[ky + 1][kx] * wv;
                s11 += p[ky + 1][kx + 1] * wv;
            }
    }
    psum[h][pos][0][co] = s00;
    psum[h][pos][1][co] = s01;
    psum[h][pos][2][co] = s10;
    psum[h][pos][3][co] = s11;
    __syncthreads();
    if (h == 0) {
        const float sc = scale[co], bs = bias2[co];
        float v = 0.f;
        #pragma unroll
        for (int k = 0; k < 4; ++k) {
            const float sk = psum[0][pos][k][co] + psum[1][pos][k][co];
            v += fmaxf(sk * sc + bs, 0.f);
        }
        feat[b * 128 + co * 4 + pos] = v * 0.25f;
    }
}

// ---------------- fused router: E2 inline + beam search + expert chain + output log_softmax
// one block (256 threads) per sample; 32-lane group g = beam; lane owns j = 4l..4l+3
__global__ __launch_bounds__(256) void router_k(
    const float* __restrict__ feat, const float* __restrict__ Whh,
    const float* __restrict__ Who, const float* __restrict__ bo,
    const float* __restrict__ emb, const float* __restrict__ Wxh,
    const float* __restrict__ bh, const float* __restrict__ Wexp,
    const float* __restrict__ bexp, const float* __restrict__ Wout,
    const float* __restrict__ bout, float* __restrict__ out)
{
    const int b = blockIdx.x, tid = threadIdx.x;
    const int g = tid >> 5, l = tid & 31, j0 = l * 4;
    __shared__ __align__(16) float fs[128];
    __shared__ __align__(16) float hbuf[2][8][128];
    __shared__ __align__(16) float E2s[3][128];
    __shared__ float total[24];
    __shared__ float scores[8];
    __shared__ int bi[8];
    __shared__ int opsel[8];
    __shared__ int oph[3][8];
    __shared__ int oph2[3][8];

    if (tid < 128) fs[tid] = feat[b * 128 + tid];
    // E2[o][j] = (emb[o] @ Wxh)[j] + bh[j], inlined (384 outputs over 256 threads)
    for (int i = tid; i < 384; i += 256) {
        const int o = i >> 7, j = i & 127;
        float a = bh[j];
        #pragma unroll 4
        for (int d = 0; d < 128; ++d) a += emb[o * 128 + d] * Wxh[d * 128 + j];
        E2s[o][j] = a;
    }
    if (l == 0) scores[g] = (g == 0) ? 0.f : -1.0e9f;   // wave-local: only group g's lane 0 reads it
    __syncthreads();
    // hr init: broadcast feat to all 8 beams (own-row write, wave-synchronous)
    {
        const float4 f4 = *reinterpret_cast<const float4*>(&fs[j0]);
        *reinterpret_cast<float4*>(&hbuf[0][g][j0]) = f4;
    }

    int cur = 0;
    for (int t = 0; t < 3; ++t) {
        // ---- logits (own row, no barrier needed after init/update by same wave)
        {
            float p0 = 0.f, p1 = 0.f, p2 = 0.f;
            #pragma unroll
            for (int dd = 0; dd < 4; ++dd) {
                const int d = l + 32 * dd;
                const float hv = hbuf[cur][g][d];
                p0 += hv * Who[d * 3 + 0];
                p1 += hv * Who[d * 3 + 1];
                p2 += hv * Who[d * 3 + 2];
            }
            #pragma unroll
            for (int s = 16; s > 0; s >>= 1) {
                p0 += __shfl_down(p0, s, 32);
                p1 += __shfl_down(p1, s, 32);
                p2 += __shfl_down(p2, s, 32);
            }
            if (l == 0) {
                const float t0 = (p0 + bo[0]) / 0.4f;
                const float t1 = (p1 + bo[1]) / 0.4f;
                const float t2 = (p2 + bo[2]) / 0.4f;
                const float mm = fmaxf(t0, fmaxf(t1, t2));
                const float lse = mm + logf(expf(t0 - mm) + expf(t1 - mm) + expf(t2 - mm));
                const float sc = scores[g];
                total[g * 3 + 0] = sc + (t0 - lse);
                total[g * 3 + 1] = sc + (t1 - lse);
                total[g * 3 + 2] = sc + (t2 - lse);
            }
        }
        __syncthreads();
        // ---- stable top-8, register-resident (static indices only; first-index-wins ties)
        if (tid == 0) {
            float tv[24];
            #pragma unroll
            for (int i = 0; i < 24; ++i) tv[i] = total[i];
            unsigned mask = 0;
            for (int r = 0; r < 8; ++r) {
                float best = -INFINITY; int idx = 0;
                #pragma unroll
                for (int i = 0; i < 24; ++i) {
                    if (!(mask & (1u << i)) && tv[i] > best) { best = tv[i]; idx = i; }
                }
                mask |= 1u << idx;
                scores[r] = best;
                bi[r] = idx / 3;
                opsel[r] = idx % 3;
            }
            for (int r = 0; r < 8; ++r) {
                for (int s = 0; s < t; ++s) oph2[s][r] = oph[s][bi[r]];
                oph2[t][r] = opsel[r];
            }
            for (int r = 0; r < 8; ++r)
                for (int s = 0; s <= t; ++s) oph[s][r] = oph2[s][r];
        }
        __syncthreads();
        // ---- hr[g] = tanh(hr[bi[g]] @ Whh + E2[opsel[g]])   (beam gather = cross-wave read)
        {
            const int o = opsel[g], src = bi[g];
            float4 a = *reinterpret_cast<const float4*>(&E2s[o][j0]);
            const float* hrow = &hbuf[cur][src][0];
            #pragma unroll 4
            for (int d = 0; d < 128; ++d) {
                const float rv = hrow[d];
                const float4 w4 = *reinterpret_cast<const float4*>(&Whh[d * 128 + j0]);
                a.x += rv * w4.x; a.y += rv * w4.y; a.z += rv * w4.z; a.w += rv * w4.w;
            }
            float4 tr;
            tr.x = tanhf(a.x); tr.y = tanhf(a.y); tr.z = tanhf(a.z); tr.w = tanhf(a.w);
            const int nxt = cur ^ 1;
            *reinterpret_cast<float4*>(&hbuf[nxt][g][j0]) = tr;
        }
        cur ^= 1;
        __syncthreads();   // protects next iteration's cross-wave gather AND expert-phase buffer reuse
    }

    // ---- expert chain: own-row only from here -> zero barriers (32-lane group is wave-synchronous)
    {
        const float4 f4 = *reinterpret_cast<const float4*>(&fs[j0]);
        *reinterpret_cast<float4*>(&hbuf[0][g][j0]) = f4;
    }
    int c2 = 0;
    for (int t = 0; t < 3; ++t) {
        const int o = oph[t][g];
        const float* wbase = &Wexp[o * 16384];
        float4 a = *reinterpret_cast<const float4*>(&bexp[o * 128 + j0]);
        const float* hrow = &hbuf[c2][g][0];
        #pragma unroll 4
        for (int d = 0; d < 128; ++d) {
            const float rv = hrow[d];
            const float4 w4 = *reinterpret_cast<const float4*>(&wbase[d * 128 + j0]);
            a.x += rv * w4.x; a.y += rv * w4.y; a.z += rv * w4.z; a.w += rv * w4.w;
        }
        float4 rr;
        rr.x = fmaxf(a.x, 0.f); rr.y = fmaxf(a.y, 0.f);
        rr.z = fmaxf(a.z, 0.f); rr.w = fmaxf(a.w, 0.f);
        const int nxt = c2 ^ 1;
        *reinterpret_cast<float4*>(&hbuf[nxt][g][j0]) = rr;
        c2 ^= 1;
    }

    // ---- out = log_softmax(hs @ Wout + bout): lanes 0..9 per group, butterfly LSE
    {
        float acc = 0.f;
        if (l < 10) {
            acc = bout[l];
            const float* hrow = &hbuf[c2][g][0];
            #pragma unroll 4
            for (int d = 0; d < 128; ++d) acc += hrow[d] * Wout[d * 10 + l];
        }
        float mm = (l < 10) ? acc : -INFINITY;
        #pragma unroll
        for (int s = 16; s > 0; s >>= 1) mm = fmaxf(mm, __shfl_xor(mm, s, 32));
        float ex = (l < 10) ? expf(acc - mm) : 0.f;
        float sum = ex;
        #pragma unroll
        for (int s = 16; s > 0; s >>= 1) sum += __shfl_xor(sum, s, 32);
        const float lse = mm + logf(sum);
        if (l < 10) out[(b * 8 + g) * 10 + l] = acc - lse;
    }
}

extern "C" void kernel_launch(void* const* d_in, const int* in_sizes, int n_in,
                              void* d_out, int out_size, void* d_ws, size_t ws_size,
                              hipStream_t stream) {
    (void)in_sizes; (void)n_in; (void)out_size; (void)ws_size;
    const float* x    = (const float*)d_in[0];
    const float* c1w  = (const float*)d_in[1];
    const float* c1b  = (const float*)d_in[2];
    const float* g1   = (const float*)d_in[3];
    const float* b1   = (const float*)d_in[4];
    const float* m1   = (const float*)d_in[5];
    const float* v1   = (const float*)d_in[6];
    const float* c2w  = (const float*)d_in[7];
    const float* c2b  = (const float*)d_in[8];
    const float* g2   = (const float*)d_in[9];
    const float* b2   = (const float*)d_in[10];
    const float* m2   = (const float*)d_in[11];
    const float* v2   = (const float*)d_in[12];
    const float* c3w  = (const float*)d_in[13];
    const float* c3b  = (const float*)d_in[14];
    const float* g3   = (const float*)d_in[15];
    const float* b3   = (const float*)d_in[16];
    const float* m3   = (const float*)d_in[17];
    const float* v3   = (const float*)d_in[18];
    const float* Wxh  = (const float*)d_in[19];
    const float* Whh  = (const float*)d_in[20];
    const float* bh   = (const float*)d_in[21];
    const float* Who  = (const float*)d_in[22];
    const float* bo   = (const float*)d_in[23];
    const float* emb  = (const float*)d_in[24];
    const float* Wexp = (const float*)d_in[25];
    const float* bexp = (const float*)d_in[26];
    const float* Wout = (const float*)d_in[27];
    const float* bout = (const float*)d_in[28];

    float* ws   = (float*)d_ws;
    float* h1   = ws;                    // 512*7200
    float* h2   = h1 + 3686400;          // 512*1152
    float* feat = h2 + 589824;           // 512*128

    conv1_k<<<512, 512, 0, stream>>>(x, c1w, c1b, g1, b1, m1, v1, h1);
    conv2_k<<<512, 384, 0, stream>>>(h1, c2w, c2b, g2, b2, m2, v2, h2);
    conv3_k<<<512, 256, 0, stream>>>(h2, c3w, c3b, g3, b3, m3, v3, feat);
    router_k<<<512, 256, 0, stream>>>(feat, Whh, Who, bo, emb, Wxh, bh,
                                      Wexp, bexp, Wout, bout, (float*)d_out);
}

// Round 8
// 244.889 us; speedup vs baseline: 1.1241x; 1.1241x over previous
//
#include <hip/hip_runtime.h>
#include <math.h>

// ---------------- conv1: (512,1,32,32) -> conv3x3(32ch) -> BN -> ReLU -> pool2 -> h1 (512,32,15,15)
__global__ __launch_bounds__(512) void conv1_k(
    const float* __restrict__ x, const float* __restrict__ w,
    const float* __restrict__ cb, const float* __restrict__ bg,
    const float* __restrict__ bb, const float* __restrict__ bm,
    const float* __restrict__ bv, float* __restrict__ h1)
{
    __shared__ float img[32 * 33];            // row stride 33 -> conflict-free broadcast reads
    __shared__ float ws_[288];
    __shared__ float scale[32], bias2[32];
    const int b = blockIdx.x, tid = threadIdx.x;
    for (int i = tid; i < 1024; i += 512) {
        const int y = i >> 5, xx = i & 31;
        img[y * 33 + xx] = x[b * 1024 + i];
    }
    if (tid < 288) ws_[tid] = w[tid];
    if (tid < 32) {
        float inv = bg[tid] / sqrtf(bv[tid] + 1e-5f);
        scale[tid] = inv;
        bias2[tid] = (cb[tid] - bm[tid]) * inv + bb[tid];
    }
    __syncthreads();

    const int co = tid >> 4, py = tid & 15;
    if (py < 15) {
        float acc0[30], acc1[30];
        #pragma unroll
        for (int i = 0; i < 30; ++i) { acc0[i] = 0.f; acc1[i] = 0.f; }
        const float* w9 = &ws_[co * 9];
        #pragma unroll
        for (int ir = 0; ir < 4; ++ir) {
            const int y = 2 * py + ir;
            float wk0 = 0.f, wk1 = 0.f, wk2 = 0.f, wl0 = 0.f, wl1 = 0.f, wl2 = 0.f;
            if (ir <= 2) { wk0 = w9[ir * 3 + 0]; wk1 = w9[ir * 3 + 1]; wk2 = w9[ir * 3 + 2]; }
            if (ir >= 1) { wl0 = w9[(ir - 1) * 3 + 0]; wl1 = w9[(ir - 1) * 3 + 1]; wl2 = w9[(ir - 1) * 3 + 2]; }
            #pragma unroll
            for (int xx = 0; xx < 32; ++xx) {
                const float rv = img[y * 33 + xx];
                if (ir <= 2) {
                    if (xx <= 29) acc0[xx] += rv * wk0;
                    if (xx >= 1 && xx <= 30) acc0[xx - 1] += rv * wk1;
                    if (xx >= 2) acc0[xx - 2] += rv * wk2;
                }
                if (ir >= 1) {
                    if (xx <= 29) acc1[xx] += rv * wl0;
                    if (xx >= 1 && xx <= 30) acc1[xx - 1] += rv * wl1;
                    if (xx >= 2) acc1[xx - 2] += rv * wl2;
                }
            }
        }
        const float sc = scale[co], bs = bias2[co];
        #pragma unroll
        for (int px = 0; px < 15; ++px) {
            const float v = fmaxf(acc0[2 * px] * sc + bs, 0.f)
                          + fmaxf(acc0[2 * px + 1] * sc + bs, 0.f)
                          + fmaxf(acc1[2 * px] * sc + bs, 0.f)
                          + fmaxf(acc1[2 * px + 1] * sc + bs, 0.f);
            h1[b * 7200 + co * 225 + py * 15 + px] = v * 0.25f;
        }
    }
}

// ---------------- conv2: h1 (512,32,15,15) -> conv3x3(32ch) -> BN -> ReLU -> pool2 -> h2 (512,32,6,6)
__global__ __launch_bounds__(384) void conv2_k(
    const float* __restrict__ h1, const float* __restrict__ w,
    const float* __restrict__ cb, const float* __restrict__ bg,
    const float* __restrict__ bb, const float* __restrict__ bm,
    const float* __restrict__ bv, float* __restrict__ h2)
{
    __shared__ float in_s[32 * 210];
    __shared__ float w_s[9216];               // transposed: w_s[k*32 + co]
    __shared__ float scale[32], bias2[32];
    const int b = blockIdx.x, tid = threadIdx.x;
    for (int i = tid; i < 6720; i += 384) {
        const int ci = i / 210, rem = i % 210;
        in_s[i] = h1[b * 7200 + ci * 225 + rem];
    }
    for (int i = tid; i < 9216; i += 384) {
        const int co = i & 31, k = i >> 5;
        w_s[i] = w[co * 288 + k];
    }
    if (tid < 32) {
        float inv = bg[tid] / sqrtf(bv[tid] + 1e-5f);
        scale[tid] = inv;
        bias2[tid] = (cb[tid] - bm[tid]) * inv + bb[tid];
    }
    __syncthreads();

    const int co = tid & 31, g = tid >> 5;
    const int py = g >> 1, xh = g & 1;
    const int gx0 = xh * 6;
    float acc0[6], acc1[6];
    #pragma unroll
    for (int i = 0; i < 6; ++i) { acc0[i] = 0.f; acc1[i] = 0.f; }

    for (int ci = 0; ci < 32; ++ci) {
        float w9[9];
        #pragma unroll
        for (int kk = 0; kk < 9; ++kk) w9[kk] = w_s[(ci * 9 + kk) * 32 + co];
        const float* ip = &in_s[ci * 210];
        #pragma unroll
        for (int ir = 0; ir < 4; ++ir) {
            const int y = 2 * py + ir;
            const float* rowp = &ip[y * 15 + gx0];
            #pragma unroll
            for (int xx = 0; xx < 8; ++xx) {
                const float rv = rowp[xx];
                if (ir <= 2) {
                    if (xx <= 5) acc0[xx] += rv * w9[ir * 3 + 0];
                    if (xx >= 1 && xx <= 6) acc0[xx - 1] += rv * w9[ir * 3 + 1];
                    if (xx >= 2) acc0[xx - 2] += rv * w9[ir * 3 + 2];
                }
                if (ir >= 1) {
                    if (xx <= 5) acc1[xx] += rv * w9[(ir - 1) * 3 + 0];
                    if (xx >= 1 && xx <= 6) acc1[xx - 1] += rv * w9[(ir - 1) * 3 + 1];
                    if (xx >= 2) acc1[xx - 2] += rv * w9[(ir - 1) * 3 + 2];
                }
            }
        }
    }
    const float sc = scale[co], bs = bias2[co];
    #pragma unroll
    for (int pxl = 0; pxl < 3; ++pxl) {
        const float v = fmaxf(acc0[2 * pxl] * sc + bs, 0.f)
                      + fmaxf(acc0[2 * pxl + 1] * sc + bs, 0.f)
                      + fmaxf(acc1[2 * pxl] * sc + bs, 0.f)
                      + fmaxf(acc1[2 * pxl + 1] * sc + bs, 0.f);
        h2[b * 1152 + co * 36 + py * 6 + xh * 3 + pxl] = v * 0.25f;
    }
}

// ---------------- conv3: h2 (512,32,6,6) -> conv3x3(32ch) -> BN -> ReLU -> pool2 -> feat (512,128)
__global__ __launch_bounds__(256) void conv3_k(
    const float* __restrict__ h2, const float* __restrict__ w,
    const float* __restrict__ cb, const float* __restrict__ bg,
    const float* __restrict__ bb, const float* __restrict__ bm,
    const float* __restrict__ bv, float* __restrict__ feat)
{
    __shared__ float in_s[1152];
    __shared__ float w_s[9216];               // w_s[k*32 + co], k = ci*9 + kk
    __shared__ float psum[2][4][4][33];       // [h][pos][k][co], stride-33 pad
    __shared__ float scale[32], bias2[32];
    const int b = blockIdx.x, tid = threadIdx.x;
    for (int i = tid; i < 1152; i += 256) in_s[i] = h2[b * 1152 + i];
    for (int i = tid; i < 9216; i += 256) {
        const int co = i & 31, k = i >> 5;
        w_s[i] = w[co * 288 + k];
    }
    if (tid < 32) {
        float inv = bg[tid] / sqrtf(bv[tid] + 1e-5f);
        scale[tid] = inv;
        bias2[tid] = (cb[tid] - bm[tid]) * inv + bb[tid];
    }
    __syncthreads();

    const int co = tid & 31, g = tid >> 5;
    const int pos = g & 3, h = g >> 2;
    const int y0 = (pos >> 1) * 2, x0 = (pos & 1) * 2;
    float s00 = 0.f, s01 = 0.f, s10 = 0.f, s11 = 0.f;
    for (int ci = h * 16; ci < h * 16 + 16; ++ci) {
        float w9[9];
        #pragma unroll
        for (int kk = 0; kk < 9; ++kk) w9[kk] = w_s[(ci * 9 + kk) * 32 + co];
        const float* ip = &in_s[ci * 36 + y0 * 6 + x0];
        float p[4][4];
        #pragma unroll
        for (int i = 0; i < 4; ++i)
            #pragma unroll
            for (int j = 0; j < 4; ++j)
                p[i][j] = ip[i * 6 + j];
        #pragma unroll
        for (int ky = 0; ky < 3; ++ky)
            #pragma unroll
            for (int kx = 0; kx < 3; ++kx) {
                const float wv = w9[ky * 3 + kx];
                s00 += p[ky][kx] * wv;
                s01 += p[ky][kx + 1] * wv;
                s10 += p[ky + 1][kx] * wv;
                s11 += p[ky + 1][kx + 1] * wv;
            }
    }
    psum[h][pos][0][co] = s00;
    psum[h][pos][1][co] = s01;
    psum[h][pos][2][co] = s10;
    psum[h][pos][3][co] = s11;
    __syncthreads();
    if (h == 0) {
        const float sc = scale[co], bs = bias2[co];
        float v = 0.f;
        #pragma unroll
        for (int k = 0; k < 4; ++k) {
            const float sk = psum[0][pos][k][co] + psum[1][pos][k][co];
            v += fmaxf(sk * sc + bs, 0.f);
        }
        feat[b * 128 + co * 4 + pos] = v * 0.25f;
    }
}

// ---------------- E2[o][j] = (emb[o] @ Wxh)[j] + bh[j]  (1 block, once)
__global__ __launch_bounds__(384) void e2_k(
    const float* __restrict__ emb, const float* __restrict__ Wxh,
    const float* __restrict__ bh, float* __restrict__ E2)
{
    const int t = threadIdx.x;
    const int o = t >> 7, j = t & 127;
    float a = bh[j];
    float a2 = 0.f;
    #pragma unroll 4
    for (int d = 0; d < 64; ++d) {
        a  += emb[o * 128 + d] * Wxh[d * 128 + j];
        a2 += emb[o * 128 + d + 64] * Wxh[(d + 64) * 128 + j];
    }
    E2[t] = a + a2;
}

// ---------------- router: beam search + expert chain + output log_softmax
// 512 threads/sample. thread = (j = tid&127, q = tid>>7 d-quarter).
// Beam update: one Whh load feeds 8 beams (Whh read 1x/block/step); psum combine.
// Expert: 3 weight streams + per-beam cndmask select (Wexp read 3x64KB/block/step).
__global__ __launch_bounds__(512, 4) void router_k(
    const float* __restrict__ feat, const float* __restrict__ Whh,
    const float* __restrict__ Who, const float* __restrict__ bo,
    const float* __restrict__ E2, const float* __restrict__ Wexp,
    const float* __restrict__ bexp, const float* __restrict__ Wout,
    const float* __restrict__ bout, float* __restrict__ out)
{
    const int b = blockIdx.x, tid = threadIdx.x;
    const int j = tid & 127, q = tid >> 7;
    __shared__ float hbuf[2][8][128];
    __shared__ float E2s[3][128];
    __shared__ float bexps[3][128];
    __shared__ float psum[4][8][128];
    __shared__ float total[24], scores[8];
    __shared__ int bi[8], opsel[8], oph[3][8], oph2[3][8];

    const float fv = feat[b * 128 + j];       // kept in register for both inits
    hbuf[0][2 * q][j] = fv;
    hbuf[0][2 * q + 1][j] = fv;
    for (int i = tid; i < 384; i += 512) {
        (&E2s[0][0])[i] = E2[i];
        (&bexps[0][0])[i] = bexp[i];
    }
    if (tid < 8) scores[tid] = (tid == 0) ? 0.f : -1.0e9f;
    __syncthreads();

    int cur = 0;
    for (int t = 0; t < 3; ++t) {
        // ---- logits + log_softmax(T=0.4): group grp<8 handles beam grp
        {
            const int grp = tid >> 5, l = tid & 31;
            if (grp < 8) {
                float p0 = 0.f, p1 = 0.f, p2 = 0.f;
                #pragma unroll
                for (int dd = 0; dd < 4; ++dd) {
                    const int d = l + 32 * dd;
                    const float hv = hbuf[cur][grp][d];
                    p0 += hv * Who[d * 3 + 0];
                    p1 += hv * Who[d * 3 + 1];
                    p2 += hv * Who[d * 3 + 2];
                }
                #pragma unroll
                for (int s = 16; s > 0; s >>= 1) {
                    p0 += __shfl_down(p0, s, 32);
                    p1 += __shfl_down(p1, s, 32);
                    p2 += __shfl_down(p2, s, 32);
                }
                if (l == 0) {
                    const float t0 = (p0 + bo[0]) / 0.4f;
                    const float t1 = (p1 + bo[1]) / 0.4f;
                    const float t2 = (p2 + bo[2]) / 0.4f;
                    const float mm = fmaxf(t0, fmaxf(t1, t2));
                    const float lse = mm + logf(expf(t0 - mm) + expf(t1 - mm) + expf(t2 - mm));
                    const float sc = scores[grp];
                    total[grp * 3 + 0] = sc + (t0 - lse);
                    total[grp * 3 + 1] = sc + (t1 - lse);
                    total[grp * 3 + 2] = sc + (t2 - lse);
                }
            }
        }
        __syncthreads();
        // ---- stable top-8 (first-index-wins ties = lax.top_k)
        if (tid == 0) {
            float tv[24];
            #pragma unroll
            for (int i = 0; i < 24; ++i) tv[i] = total[i];
            unsigned mask = 0;
            for (int r = 0; r < 8; ++r) {
                float best = -INFINITY; int idx = 0;
                #pragma unroll
                for (int i = 0; i < 24; ++i) {
                    if (!(mask & (1u << i)) && tv[i] > best) { best = tv[i]; idx = i; }
                }
                mask |= 1u << idx;
                scores[r] = best;
                bi[r] = idx / 3;
                opsel[r] = idx % 3;
            }
            for (int r = 0; r < 8; ++r) {
                for (int s = 0; s < t; ++s) oph2[s][r] = oph[s][bi[r]];
                oph2[t][r] = opsel[r];
            }
            for (int r = 0; r < 8; ++r)
                for (int s = 0; s <= t; ++s) oph[s][r] = oph2[s][r];
        }
        __syncthreads();
        // ---- quarter partials: one Whh load -> 8 beam FMAs
        {
            const float* h0 = &hbuf[cur][bi[0]][0];
            const float* h1 = &hbuf[cur][bi[1]][0];
            const float* h2 = &hbuf[cur][bi[2]][0];
            const float* h3 = &hbuf[cur][bi[3]][0];
            const float* h4 = &hbuf[cur][bi[4]][0];
            const float* h5 = &hbuf[cur][bi[5]][0];
            const float* h6 = &hbuf[cur][bi[6]][0];
            const float* h7 = &hbuf[cur][bi[7]][0];
            float a0 = 0.f, a1 = 0.f, a2 = 0.f, a3 = 0.f, a4 = 0.f, a5 = 0.f, a6 = 0.f, a7 = 0.f;
            const int dbase = q * 32;
            const float* wp = &Whh[dbase * 128 + j];
            #pragma unroll 4
            for (int dd = 0; dd < 32; ++dd) {
                const int d = dbase + dd;
                const float wv = wp[dd * 128];
                a0 += h0[d] * wv; a1 += h1[d] * wv; a2 += h2[d] * wv; a3 += h3[d] * wv;
                a4 += h4[d] * wv; a5 += h5[d] * wv; a6 += h6[d] * wv; a7 += h7[d] * wv;
            }
            psum[q][0][j] = a0; psum[q][1][j] = a1; psum[q][2][j] = a2; psum[q][3][j] = a3;
            psum[q][4][j] = a4; psum[q][5][j] = a5; psum[q][6][j] = a6; psum[q][7][j] = a7;
        }
        __syncthreads();
        // ---- combine + tanh: thread (j,q) owns rows 2q, 2q+1
        {
            const int nxt = cur ^ 1;
            #pragma unroll
            for (int rr = 0; rr < 2; ++rr) {
                const int r = 2 * q + rr;
                const float v = psum[0][r][j] + psum[1][r][j] + psum[2][r][j] + psum[3][r][j]
                              + E2s[opsel[r]][j];
                hbuf[nxt][r][j] = tanhf(v);
            }
        }
        cur ^= 1;
        __syncthreads();
    }

    // ---- expert chain: hs = feat; 3 steps of relu(hs @ Wexp[o] + bexp[o])
    hbuf[0][2 * q][j] = fv;
    hbuf[0][2 * q + 1][j] = fv;
    __syncthreads();
    int c2 = 0;
    for (int t = 0; t < 3; ++t) {
        const int o0 = oph[t][0], o1 = oph[t][1], o2 = oph[t][2], o3 = oph[t][3];
        const int o4 = oph[t][4], o5 = oph[t][5], o6 = oph[t][6], o7 = oph[t][7];
        {
            const float* h0 = &hbuf[c2][0][0];
            const float* h1 = &hbuf[c2][1][0];
            const float* h2 = &hbuf[c2][2][0];
            const float* h3 = &hbuf[c2][3][0];
            const float* h4 = &hbuf[c2][4][0];
            const float* h5 = &hbuf[c2][5][0];
            const float* h6 = &hbuf[c2][6][0];
            const float* h7 = &hbuf[c2][7][0];
            float a0 = 0.f, a1 = 0.f, a2 = 0.f, a3 = 0.f, a4 = 0.f, a5 = 0.f, a6 = 0.f, a7 = 0.f;
            const int dbase = q * 32;
            const float* wp = &Wexp[dbase * 128 + j];
            #pragma unroll 4
            for (int dd = 0; dd < 32; ++dd) {
                const int d = dbase + dd;
                const float w0 = wp[dd * 128];
                const float w1 = wp[dd * 128 + 16384];
                const float w2 = wp[dd * 128 + 32768];
                a0 += h0[d] * (o0 == 2 ? w2 : (o0 == 1 ? w1 : w0));
                a1 += h1[d] * (o1 == 2 ? w2 : (o1 == 1 ? w1 : w0));
                a2 += h2[d] * (o2 == 2 ? w2 : (o2 == 1 ? w1 : w0));
                a3 += h3[d] * (o3 == 2 ? w2 : (o3 == 1 ? w1 : w0));
                a4 += h4[d] * (o4 == 2 ? w2 : (o4 == 1 ? w1 : w0));
                a5 += h5[d] * (o5 == 2 ? w2 : (o5 == 1 ? w1 : w0));
                a6 += h6[d] * (o6 == 2 ? w2 : (o6 == 1 ? w1 : w0));
                a7 += h7[d] * (o7 == 2 ? w2 : (o7 == 1 ? w1 : w0));
            }
            psum[q][0][j] = a0; psum[q][1][j] = a1; psum[q][2][j] = a2; psum[q][3][j] = a3;
            psum[q][4][j] = a4; psum[q][5][j] = a5; psum[q][6][j] = a6; psum[q][7][j] = a7;
        }
        __syncthreads();
        {
            const int nxt = c2 ^ 1;
            #pragma unroll
            for (int rr = 0; rr < 2; ++rr) {
                const int r = 2 * q + rr;
                const float v = psum[0][r][j] + psum[1][r][j] + psum[2][r][j] + psum[3][r][j]
                              + bexps[oph[t][r]][j];
                hbuf[nxt][r][j] = fmaxf(v, 0.f);
            }
        }
        c2 ^= 1;
        __syncthreads();
    }

    // ---- out = log_softmax(hs @ Wout + bout): group grp<8 = beam, lanes 0..9
    {
        const int grp = tid >> 5, l = tid & 31;
        if (grp < 8) {
            float acc = 0.f;
            if (l < 10) {
                acc = bout[l];
                float acc2 = 0.f;
                const float* hrow = &hbuf[c2][grp][0];
                #pragma unroll 4
                for (int d = 0; d < 64; ++d) {
                    acc  += hrow[d] * Wout[d * 10 + l];
                    acc2 += hrow[d + 64] * Wout[(d + 64) * 10 + l];
                }
                acc += acc2;
            }
            float mm = (l < 10) ? acc : -INFINITY;
            #pragma unroll
            for (int s = 16; s > 0; s >>= 1) mm = fmaxf(mm, __shfl_xor(mm, s, 32));
            float ex = (l < 10) ? expf(acc - mm) : 0.f;
            float sum = ex;
            #pragma unroll
            for (int s = 16; s > 0; s >>= 1) sum += __shfl_xor(sum, s, 32);
            const float lse = mm + logf(sum);
            if (l < 10) out[(b * 8 + grp) * 10 + l] = acc - lse;
        }
    }
}

extern "C" void kernel_launch(void* const* d_in, const int* in_sizes, int n_in,
                              void* d_out, int out_size, void* d_ws, size_t ws_size,
                              hipStream_t stream) {
    (void)in_sizes; (void)n_in; (void)out_size; (void)ws_size;
    const float* x    = (const float*)d_in[0];
    const float* c1w  = (const float*)d_in[1];
    const float* c1b  = (const float*)d_in[2];
    const float* g1   = (const float*)d_in[3];
    const float* b1   = (const float*)d_in[4];
    const float* m1   = (const float*)d_in[5];
    const float* v1   = (const float*)d_in[6];
    const float* c2w  = (const float*)d_in[7];
    const float* c2b  = (const float*)d_in[8];
    const float* g2   = (const float*)d_in[9];
    const float* b2   = (const float*)d_in[10];
    const float* m2   = (const float*)d_in[11];
    const float* v2   = (const float*)d_in[12];
    const float* c3w  = (const float*)d_in[13];
    const float* c3b  = (const float*)d_in[14];
    const float* g3   = (const float*)d_in[15];
    const float* b3   = (const float*)d_in[16];
    const float* m3   = (const float*)d_in[17];
    const float* v3   = (const float*)d_in[18];
    const float* Wxh  = (const float*)d_in[19];
    const float* Whh  = (const float*)d_in[20];
    const float* bh   = (const float*)d_in[21];
    const float* Who  = (const float*)d_in[22];
    const float* bo   = (const float*)d_in[23];
    const float* emb  = (const float*)d_in[24];
    const float* Wexp = (const float*)d_in[25];
    const float* bexp = (const float*)d_in[26];
    const float* Wout = (const float*)d_in[27];
    const float* bout = (const float*)d_in[28];

    float* ws   = (float*)d_ws;
    float* h1   = ws;                    // 512*7200
    float* h2   = h1 + 3686400;          // 512*1152
    float* feat = h2 + 589824;           // 512*128
    float* E2   = feat + 65536;          // 384

    e2_k<<<1, 384, 0, stream>>>(emb, Wxh, bh, E2);
    conv1_k<<<512, 512, 0, stream>>>(x, c1w, c1b, g1, b1, m1, v1, h1);
    conv2_k<<<512, 384, 0, stream>>>(h1, c2w, c2b, g2, b2, m2, v2, h2);
    conv3_k<<<512, 256, 0, stream>>>(h2, c3w, c3b, g3, b3, m3, v3, feat);
    router_k<<<512, 512, 0, stream>>>(feat, Whh, Who, bo, E2,
                                      Wexp, bexp, Wout, bout, (float*)d_out);
}